// Round 1
// baseline (635.728 us; speedup 1.0000x reference)
//
#include <hip/hip_runtime.h>

#define BT 16384
#define DK 4096
#define NE 64
#define BM 64                 // rows per block
#define KH 4                  // K quarters (split-K within block)
#define KPH (DK / KH)         // 1024
#define KC 32                 // k per chunk per quarter
#define NC (KPH / KC)         // 32 chunks
#define EPG 16                // experts per group (4 groups of 16)
#define LPAD 68               // logits LDS row stride (16B-aligned, spreads banks)
#define NPROBS (BT * NE)      // 1048576
#define NIDX (NPROBS)         // indices start (as floats)
#define NWTS (NPROBS + BT * 2)

__global__ __launch_bounds__(1024) void token_router(
    const float* __restrict__ x, const float* __restrict__ W,
    float* __restrict__ out)
{
    // x tile: [2 buf][4 kh][64 rows][32 k] = 16384 f32 = 64 KiB
    __shared__ float xs[2 * KH * BM * KC];
    __shared__ float lg[BM * LPAD];      // 17.4 KiB logits
    __shared__ float rowm[BM];
    __shared__ float rowinv[BM];

    const int tid  = threadIdx.x;
    const int lane = tid & 63;
    const int wig  = (tid >> 6) & 3;     // wave within kh-group -> expert group
    const int kh   = tid >> 8;           // 0..3 K-quarter
    const int eg   = wig;
    const int lt   = tid & 255;          // id within kh staging group
    const long rowbase = (long)blockIdx.x * BM;
    const int khbase = kh * KPH;

    float acc[EPG];
#pragma unroll
    for (int e = 0; e < EPG; ++e) acc[e] = 0.f;

    float4 streg[2];

    // coalesced global load of chunk c (linear), into registers
    auto ldg = [&](int c) {
#pragma unroll
        for (int r = 0; r < 2; ++r) {
            int seg = r * 256 + lt;          // 512 x 16B segments per chunk
            int row = seg >> 3;              // 8 segs per row
            int kl  = seg & 7;
            const float* g = x + (rowbase + row) * (long)DK + khbase + c * KC + kl * 4;
            streg[r] = *reinterpret_cast<const float4*>(g);
        }
    };
    // swizzled LDS write: kseg ^= (row&7) -> conflict-free b128 row-reads later
    auto stw = [&](int b) {
#pragma unroll
        for (int r = 0; r < 2; ++r) {
            int seg = r * 256 + lt;
            int row = seg >> 3;
            int kl  = seg & 7;
            int sw  = kl ^ (row & 7);
            *reinterpret_cast<float4*>(&xs[b * 8192 + kh * 2048 + row * KC + sw * 4]) = streg[r];
        }
    };

    ldg(0);
    stw(0);
    __syncthreads();

    for (int c = 0; c < NC; ++c) {
        if (c + 1 < NC) ldg(c + 1);      // issue next-chunk loads early (latency hides under FMAs)

        const int b  = c & 1;
        const int xb = b * 8192 + kh * 2048 + lane * KC;
        float4 xv[8];
#pragma unroll
        for (int j = 0; j < 8; ++j)
            xv[j] = *reinterpret_cast<const float4*>(&xs[xb + ((j ^ (lane & 7)) << 2)]);

        // W is wave-uniform: force scalar base so loads go to the scalar/VMEM
        // pipe (broadcast), keeping the DS pipe free.
        const int woff = __builtin_amdgcn_readfirstlane(eg * (EPG * DK) + khbase + c * KC);
        const float4* wp = reinterpret_cast<const float4*>(W + woff);
#pragma unroll
        for (int e = 0; e < EPG; ++e) {
#pragma unroll
            for (int j = 0; j < 8; ++j) {
                float4 w = wp[e * (DK / 4) + j];
                acc[e] = fmaf(xv[j].x, w.x, acc[e]);
                acc[e] = fmaf(xv[j].y, w.y, acc[e]);
                acc[e] = fmaf(xv[j].z, w.z, acc[e]);
                acc[e] = fmaf(xv[j].w, w.w, acc[e]);
            }
        }

        if (c + 1 < NC) stw((c + 1) & 1);  // write-late; safe: that buf was freed at barrier c-1
        __syncthreads();
    }

    // ---- deterministic cross-kh reduction into lg (fixed order kh0..kh3) ----
    if (kh == 0) {
#pragma unroll
        for (int e = 0; e < EPG; ++e) lg[lane * LPAD + eg * EPG + e] = acc[e];
    }
    __syncthreads();
    if (kh == 1) {
#pragma unroll
        for (int e = 0; e < EPG; ++e) lg[lane * LPAD + eg * EPG + e] += acc[e];
    }
    __syncthreads();
    if (kh == 2) {
#pragma unroll
        for (int e = 0; e < EPG; ++e) lg[lane * LPAD + eg * EPG + e] += acc[e];
    }
    __syncthreads();
    if (kh == 3) {
#pragma unroll
        for (int e = 0; e < EPG; ++e) lg[lane * LPAD + eg * EPG + e] += acc[e];
    }
    __syncthreads();

    // ---- Pass A: per-row softmax stats + top-2 (one thread per row) ----
    if (tid < BM) {
        const int row = tid;
        float m = -3.4e38f;
        for (int e = 0; e < NE; ++e) m = fmaxf(m, lg[row * LPAD + e]);
        float s = 0.f;
        float v1 = -1.f, v2 = -1.f;
        int   i1 = 0,    i2 = 0;
        for (int e = 0; e < NE; ++e) {
            float p = __expf(lg[row * LPAD + e] - m);
            s += p;
            if (p > v1)      { v2 = v1; i2 = i1; v1 = p; i1 = e; }
            else if (p > v2) { v2 = p; i2 = e; }
        }
        const float inv = 1.f / s;
        rowm[row]   = m;
        rowinv[row] = inv;
        const long grow = rowbase + row;
        const float p1 = v1 * inv, p2 = v2 * inv;
        const float dn = p1 + p2 + 1e-9f;
        out[NIDX + grow * 2 + 0] = (float)i1;   // indices compared numerically as floats
        out[NIDX + grow * 2 + 1] = (float)i2;
        out[NWTS + grow * 2 + 0] = p1 / dn;
        out[NWTS + grow * 2 + 1] = p2 / dn;
    }
    __syncthreads();

    // ---- Pass B: all 1024 threads write probs, coalesced float4 ----
    {
        const int row = tid >> 4;            // 0..63
        const int e0  = (tid & 15) << 2;     // 0..60
        const float4 l4 = *reinterpret_cast<const float4*>(&lg[row * LPAD + e0]);
        const float m = rowm[row], inv = rowinv[row];
        float4 p;
        p.x = __expf(l4.x - m) * inv;
        p.y = __expf(l4.y - m) * inv;
        p.z = __expf(l4.z - m) * inv;
        p.w = __expf(l4.w - m) * inv;
        const long grow = rowbase + row;
        *reinterpret_cast<float4*>(&out[grow * (long)NE + e0]) = p;
    }
}

extern "C" void kernel_launch(void* const* d_in, const int* in_sizes, int n_in,
                              void* d_out, int out_size, void* d_ws, size_t ws_size,
                              hipStream_t stream) {
    const float* x = (const float*)d_in[0];
    const float* W = (const float*)d_in[1];
    float* out = (float*)d_out;
    dim3 grid(BT / BM);   // 256
    dim3 block(1024);
    token_router<<<grid, block, 0, stream>>>(x, W, out);
}

// Round 2
// 197.232 us; speedup vs baseline: 3.2232x; 3.2232x over previous
//
#include <hip/hip_runtime.h>

#define BT 16384
#define DK 4096
#define NE 64
#define BM 32                 // rows per block
#define KC 64                 // k floats per chunk
#define NC (DK / KC)          // 64 chunks
#define NTHR 512
#define NPROBS (BT * NE)
#define NIDX (NPROBS)
#define NWTS (NPROBS + BT * 2)

// Block tile: 32 rows x 64 experts, K chunked by 64.
// 8 waves: wave = (rowhalf 0..1) x (expertquarter 0..3) -> 16 rows x 16 experts.
// Lane: rlg=lane>>3 (row pair), elg=lane&7 (expert pair) -> 2x2 register tile.
// X and W both staged in LDS, double-buffered. LDS layout is XOR-swizzled
// (k-quad ^ (row>>1)) via PRE-SWIZZLED GLOBAL SOURCES, so ds_writes are
// linear (conflict-free) and the lane-varying ds_read_b128 are conflict-free
// (8 distinct bank-quads x 8-way same-address broadcast).

__global__ __launch_bounds__(NTHR) void token_router(
    const float* __restrict__ x, const float* __restrict__ W,
    float* __restrict__ out)
{
    __shared__ float4 xs[2 * BM * (KC / 4)];   // 1024 float4 = 16 KB
    __shared__ float4 ws[2 * NE * (KC / 4)];   // 2048 float4 = 32 KB
    __shared__ float  lg[BM * 68];             // logits, padded stride
    __shared__ float  rowm[BM], rowinv[BM];

    const int tid  = threadIdx.x;
    const int lane = tid & 63;
    const int wv   = tid >> 6;                 // 0..7
    const int rlg  = lane >> 3;                // 0..7
    const int elg  = lane & 7;                 // 0..7
    const int r0   = (wv >> 2) * 16 + rlg * 2; // local row base (0..30)
    const int e0   = (wv & 3) * 16 + elg * 2;  // expert base (0..62)
    const long rowbase = (long)blockIdx.x * BM;

    // ---- staging sources (pre-swizzled so LDS slot s holds quad (s&15)^sw) ----
    const int srow = tid >> 4;                 // 0..31 (row for X, expert for W)
    const int sqs  = tid & 15;                 // 16B-quad slot within row
    const int ssw  = (srow >> 1) & 7;
    const float* gx  = x + (rowbase + srow) * (long)DK + ((sqs ^ ssw) << 2);
    const float* gw0 = W + (long)srow * DK + ((sqs ^ ssw) << 2);   // experts 0..31
    const float* gw1 = gw0 + 32 * (long)DK;                        // experts 32..63 (same swizzle)

    // LDS read bases (float4 units)
    const int xrb = r0 * 16;
    const int wrb = e0 * 16;

    float acc00 = 0.f, acc01 = 0.f, acc10 = 0.f, acc11 = 0.f;

    // prologue: stage chunk 0 into buffer 0 (linear ds_writes)
    {
        float4 a  = *(const float4*)(gx);
        float4 b0 = *(const float4*)(gw0);
        float4 b1 = *(const float4*)(gw1);
        xs[tid]        = a;
        ws[tid]        = b0;
        ws[512 + tid]  = b1;
    }
    __syncthreads();

    for (int c = 0; c < NC; ++c) {
        const int b = c & 1;
        float4 a, b0, b1;
        if (c + 1 < NC) {                      // issue next-chunk loads early
            a  = *(const float4*)(gx  + (c + 1) * KC);
            b0 = *(const float4*)(gw0 + (c + 1) * KC);
            b1 = *(const float4*)(gw1 + (c + 1) * KC);
        }
        const int xb = b * 512  + xrb;
        const int wb = b * 1024 + wrb;
#pragma unroll
        for (int q = 0; q < 16; ++q) {
            const float4 xv0 = xs[xb +      (q ^ rlg)];
            const float4 xv1 = xs[xb + 16 + (q ^ rlg)];
            const float4 wq0 = ws[wb +      (q ^ elg)];
            const float4 wq1 = ws[wb + 16 + (q ^ elg)];
            acc00 = fmaf(xv0.x, wq0.x, acc00);
            acc00 = fmaf(xv0.y, wq0.y, acc00);
            acc00 = fmaf(xv0.z, wq0.z, acc00);
            acc00 = fmaf(xv0.w, wq0.w, acc00);
            acc01 = fmaf(xv0.x, wq1.x, acc01);
            acc01 = fmaf(xv0.y, wq1.y, acc01);
            acc01 = fmaf(xv0.z, wq1.z, acc01);
            acc01 = fmaf(xv0.w, wq1.w, acc01);
            acc10 = fmaf(xv1.x, wq0.x, acc10);
            acc10 = fmaf(xv1.y, wq0.y, acc10);
            acc10 = fmaf(xv1.z, wq0.z, acc10);
            acc10 = fmaf(xv1.w, wq0.w, acc10);
            acc11 = fmaf(xv1.x, wq1.x, acc11);
            acc11 = fmaf(xv1.y, wq1.y, acc11);
            acc11 = fmaf(xv1.z, wq1.z, acc11);
            acc11 = fmaf(xv1.w, wq1.w, acc11);
        }
        if (c + 1 < NC) {                      // write-late into next buffer
            const int nb = (c + 1) & 1;
            xs[nb * 512 + tid]        = a;
            ws[nb * 1024 + tid]       = b0;
            ws[nb * 1024 + 512 + tid] = b1;
        }
        __syncthreads();
    }

    // ---- logits to LDS ----
    lg[(r0)     * 68 + e0]     = acc00;
    lg[(r0)     * 68 + e0 + 1] = acc01;
    lg[(r0 + 1) * 68 + e0]     = acc10;
    lg[(r0 + 1) * 68 + e0 + 1] = acc11;
    __syncthreads();

    // ---- per-row softmax stats + top-2 (one thread per row) ----
    if (tid < BM) {
        const int row = tid;
        float m = -3.4e38f;
        for (int e = 0; e < NE; ++e) m = fmaxf(m, lg[row * 68 + e]);
        float s = 0.f;
        float v1 = -1.f, v2 = -1.f;
        int   i1 = 0,    i2 = 0;
        for (int e = 0; e < NE; ++e) {
            float p = __expf(lg[row * 68 + e] - m);
            s += p;
            if (p > v1)      { v2 = v1; i2 = i1; v1 = p; i1 = e; }
            else if (p > v2) { v2 = p; i2 = e; }
        }
        const float inv = 1.f / s;
        rowm[row]   = m;
        rowinv[row] = inv;
        const long grow = rowbase + row;
        const float p1 = v1 * inv, p2 = v2 * inv;
        const float dn = p1 + p2 + 1e-9f;
        out[NIDX + grow * 2 + 0] = (float)i1;
        out[NIDX + grow * 2 + 1] = (float)i2;
        out[NWTS + grow * 2 + 0] = p1 / dn;
        out[NWTS + grow * 2 + 1] = p2 / dn;
    }
    __syncthreads();

    // ---- probs write, coalesced float4: 512 threads x 1 float4 ----
    {
        const int row = tid >> 4;
        const int e4  = (tid & 15) << 2;
        const float4 l4 = *reinterpret_cast<const float4*>(&lg[row * 68 + e4]);
        const float m = rowm[row], inv = rowinv[row];
        float4 p;
        p.x = __expf(l4.x - m) * inv;
        p.y = __expf(l4.y - m) * inv;
        p.z = __expf(l4.z - m) * inv;
        p.w = __expf(l4.w - m) * inv;
        const long grow = rowbase + row;
        *reinterpret_cast<float4*>(&out[grow * (long)NE + e4]) = p;
    }
}

extern "C" void kernel_launch(void* const* d_in, const int* in_sizes, int n_in,
                              void* d_out, int out_size, void* d_ws, size_t ws_size,
                              hipStream_t stream) {
    const float* x = (const float*)d_in[0];
    const float* W = (const float*)d_in[1];
    float* out = (float*)d_out;
    dim3 grid(BT / BM);    // 512 blocks -> 2 per CU
    dim3 block(NTHR);      // 512 threads = 8 waves
    token_router<<<grid, block, 0, stream>>>(x, W, out);
}